// Round 6
// baseline (176.366 us; speedup 1.0000x reference)
//
#include <hip/hip_runtime.h>

// x (8192,64) f32, x_var (8192,64) f32, proto_mean (19,10,64) f32,
// proto_var (19,10,64) f32  ->  out (8192,19,10) f32.
//
// out[n,cm] = -1/128 * ( sum_k (pm-x)^2/(xv+pv) + ln prod_k (xv+pv) )
//
// Round-4 retained: lane<->cm mapping, proto chunks in VGPRs (per-lane
// vector loads), coalesced stores, zero spill (fits the backend's immovable
// 84-VGPR choice -- amdgpu_waves_per_eu(3,3) was ignored in round 5).
//
// Round-6 change: row data was wave-uniform s_load (scalar path) -- rocprof
// showed VALUBusy 35% / dur 45us: streaming scalar-cache misses serialize
// instead of pipelining. Now forced onto the VECTOR path via a divergence
// hack: z = tid>>9 is always 0, but with no __launch_bounds__ the compiler
// only knows tid<=1023 (z in {0,1}) and must treat the address as divergent
// -> global_load_dwordx4, vmcnt-pipelined, HW-coalesced broadcast (all
// lanes same address = one L1 request). KC=16->8 for finer pipelining
// within the register cap (prod of 8 v in [1,2) < 2^8 -- exact).
#define NROWS 8192
#define KDIM  64
#define CMDIM 190
#define RPB   4        // rows per block -> 2048 blocks of 192 threads
#define KC    8        // k per chunk; 1 log per 8 k

__global__ void probproto_kernel(const float* __restrict__ x,
                                 const float* __restrict__ xv,
                                 const float* __restrict__ pm,
                                 const float* __restrict__ pv,
                                 float* __restrict__ out)
{
    const int t  = threadIdx.x;                  // 0..191, t == cm
    const int cm = t < CMDIM ? t : CMDIM - 1;    // clamp for loads
    const int n0 = blockIdx.x * RPB;

    // z == 0 always; compiler can't prove it (tid range 0..1023 w/o
    // launch_bounds, and workitem-id is conservatively divergent).
    const int z = (int)(threadIdx.x >> 9);

    float accQ[RPB] = {0.f, 0.f, 0.f, 0.f};
    float accL[RPB] = {0.f, 0.f, 0.f, 0.f};

    #pragma unroll
    for (int c = 0; c < KDIM / KC; ++c) {
        // ---- proto chunk -> 16 VGPRs (per-lane addresses, reused 4 rows) ----
        float pmc[KC], pvc[KC];
        {
            const float4* pm4 = (const float4*)(pm + (size_t)cm * KDIM + c * KC);
            const float4* pv4 = (const float4*)(pv + (size_t)cm * KDIM + c * KC);
            #pragma unroll
            for (int i = 0; i < KC / 4; ++i) {
                float4 a = pm4[i], b = pv4[i];
                pmc[4*i+0] = a.x; pmc[4*i+1] = a.y; pmc[4*i+2] = a.z; pmc[4*i+3] = a.w;
                pvc[4*i+0] = b.x; pvc[4*i+1] = b.y; pvc[4*i+2] = b.z; pvc[4*i+3] = b.w;
            }
        }

        #pragma unroll
        for (int r = 0; r < RPB; ++r) {
            // Uniform-in-fact addresses made formally divergent by +z:
            // -> global_load_dwordx4 (vector path, vmcnt pipelining).
            const float4* xr4 = (const float4*)(x  + (size_t)(n0 + r) * KDIM + c * KC) + z;
            const float4* vr4 = (const float4*)(xv + (size_t)(n0 + r) * KDIM + c * KC) + z;
            float4 xa = xr4[0], xb = xr4[1];     // x[k..k+7]   (broadcast)
            float4 va = vr4[0], vb = vr4[1];     // xv[k..k+7]  (broadcast)

            float xc[KC] = {xa.x, xa.y, xa.z, xa.w, xb.x, xb.y, xb.z, xb.w};
            float vc[KC] = {va.x, va.y, va.z, va.w, vb.x, vb.y, vb.z, vb.w};

            float q0 = 0.f, q1 = 0.f;            // 2 indep rcp-fma chains
            float p0 = 1.f, p1 = 1.f;            // 2 product chains
            #pragma unroll
            for (int k = 0; k < KC; k += 2) {
                float v0 = vc[k+0] + pvc[k+0], d0 = xc[k+0] - pmc[k+0];
                float v1 = vc[k+1] + pvc[k+1], d1 = xc[k+1] - pmc[k+1];
                q0 = fmaf(d0 * d0, __builtin_amdgcn_rcpf(v0), q0);
                q1 = fmaf(d1 * d1, __builtin_amdgcn_rcpf(v1), q1);
                p0 *= v0; p1 *= v1;
            }
            accQ[r] += q0 + q1;
            accL[r] += __log2f(p0 * p1);         // 1 log per 8 k
        }
    }

    #pragma unroll
    for (int r = 0; r < RPB; ++r) {
        float res = -(accQ[r] + 0.69314718055994531f * accL[r]) * (1.0f / 128.0f);
        if (t < CMDIM)
            out[(size_t)(n0 + r) * CMDIM + t] = res;     // coalesced
    }
}

extern "C" void kernel_launch(void* const* d_in, const int* in_sizes, int n_in,
                              void* d_out, int out_size, void* d_ws, size_t ws_size,
                              hipStream_t stream) {
    const float* x  = (const float*)d_in[0];
    const float* xv = (const float*)d_in[1];
    const float* pm = (const float*)d_in[2];
    const float* pv = (const float*)d_in[3];
    float* out = (float*)d_out;

    probproto_kernel<<<NROWS / RPB, 192, 0, stream>>>(x, xv, pm, pv, out);
}